// Round 15
// baseline (123.967 us; speedup 1.0000x reference)
//
#include <hip/hip_runtime.h>
#include <hip/hip_bf16.h>

typedef __bf16 bf16;
typedef __bf16 bf16x4 __attribute__((ext_vector_type(4)));
typedef __bf16 bf16x8 __attribute__((ext_vector_type(8)));
typedef float  f32x4  __attribute__((ext_vector_type(4)));

#define GLD_LDS(g, l) __builtin_amdgcn_global_load_lds(                        \
    (const __attribute__((address_space(1))) unsigned int*)(g),                \
    (__attribute__((address_space(3))) unsigned int*)(l), 16, 0, 0)

// ---------------- f32 -> bf16 conversion (weights only) ---------------------
struct CvtSegs {
  const float* src[4];
  bf16* dst[4];
  int n8[4];
  int total8;
};

__global__ __launch_bounds__(256) void cvt_all(CvtSegs s) {
  int i = blockIdx.x * 256 + threadIdx.x;
  if (i >= s.total8) return;
  int seg = 0, off = i;
  while (off >= s.n8[seg]) { off -= s.n8[seg]; ++seg; }
  const float4* sp = reinterpret_cast<const float4*>(s.src[seg]);
  float4 a = sp[2 * off], b = sp[2 * off + 1];
  bf16x8 o;
  o[0] = (bf16)a.x; o[1] = (bf16)a.y; o[2] = (bf16)a.z; o[3] = (bf16)a.w;
  o[4] = (bf16)b.x; o[5] = (bf16)b.y; o[6] = (bf16)b.z; o[7] = (bf16)b.w;
  reinterpret_cast<bf16x8*>(s.dst[seg])[off] = o;
}

// ---------------- QKV GEMM: 128x64 tiles, f32-A direct, 2-phase dbuf --------
// C = A_f32(4096,1024) * B_bf16(1024,1024)^T + bias.  Grid (16,32,3) = 1536
// blocks = 6/CU grid-wise; 40KB LDS -> 4 blocks/CU resident (vs 3 at 128^2):
// block-level TLP is the binding constraint (gemm_out 128x64 evidence).
// A staged RAW f32 via global_load_lds (source-chunk swizzle), fragments
// cvt'd on ds_read; B bf16 1 GLD/iter.  STAGE(t+1) before compute(t),
// single vmcnt(0)+s_barrier per iter.  z==2 writes V^T [bh][d][s].
__global__ __launch_bounds__(256) void gemm_qkv(
    const float* __restrict__ A0, const float* __restrict__ A1, const float* __restrict__ A2,
    const bf16* __restrict__ B0, const bf16* __restrict__ B1, const bf16* __restrict__ B2,
    const float* __restrict__ bias0, const float* __restrict__ bias1, const float* __restrict__ bias2,
    bf16* __restrict__ C0, bf16* __restrict__ C1, bf16* __restrict__ C2) {
  const int f = blockIdx.x + (blockIdx.y << 4) + (blockIdx.z << 9);
  const int g = (f & 7) * 192 + (f >> 3);  // 1536 % 8 == 0: bijective
  const int bn = g & 15;
  const int bm = (g >> 4) & 31;
  const int z = g >> 9;

  const float* A = (z == 0) ? A0 : (z == 1) ? A1 : A2;
  const bf16* B = (z == 0) ? B0 : (z == 1) ? B1 : B2;
  const float* bias = (z == 0) ? bias0 : (z == 1) ? bias1 : bias2;
  bf16* C = (z == 0) ? C0 : (z == 1) ? C1 : C2;

  const int t = threadIdx.x;
  const int lane = t & 63, w = t >> 6;
  const int lr = lane & 15, lk = lane >> 4;
  const int wm = w >> 1, wn = w & 1;

  __shared__ __align__(16) float Afs[2][128 * 32];   // 2 x 16KB
  __shared__ __align__(16) bf16  Bs[2][64 * 32];     // 2 x 4KB

  auto STAGE = [&](int buf, int kt) {
#pragma unroll
    for (int gg = 0; gg < 4; ++gg) {
      const int row = w * 32 + gg * 8 + (lane >> 3);
      const int cg = (lane & 7) ^ (row & 7);  // pre-swizzled source chunk
      GLD_LDS(A + (size_t)(bm * 128 + row) * 1024 + kt * 32 + cg * 4,
              &Afs[buf][(w * 32 + gg * 8) * 32]);
    }
    {
      const int row = t >> 2;            // [0,64)
      const int col = (t & 3) * 8;
      const int ldso = (t & ~63) * 8;    // wave-uniform LDS base (elems)
      GLD_LDS(B + (size_t)(bn * 64 + row) * 1024 + kt * 32 + col, &Bs[buf][ldso]);
    }
  };

  f32x4 acc[4][2];
#pragma unroll
  for (int m = 0; m < 4; ++m)
#pragma unroll
    for (int n = 0; n < 2; ++n) acc[m][n] = {0.f, 0.f, 0.f, 0.f};

  // prologue: tile 0 staged and drained
  STAGE(0, 0);
  asm volatile("s_waitcnt vmcnt(0)" ::: "memory");
  __builtin_amdgcn_s_barrier();

  for (int kt = 0; kt < 32; ++kt) {
    const int cur = kt & 1;
    if (kt < 31) STAGE(cur ^ 1, kt + 1);  // in flight across compute phase
    __builtin_amdgcn_sched_barrier(0);

    // --- fragments: A f32 -> cvt bf16; B direct -----------------------------
    char* AfB = (char*)&Afs[cur][0];
    bf16x8 af[4], bfr[2];
#pragma unroll
    for (int m = 0; m < 4; ++m) {
      const int row = wm * 64 + m * 16 + lr;
      const int sw = row & 7;
      const int b0 = row * 128 + ((2 * lk) ^ sw) * 16;
      const int b1 = row * 128 + ((2 * lk + 1) ^ sw) * 16;
      f32x4 lo = *(const f32x4*)(AfB + b0);
      f32x4 hi = *(const f32x4*)(AfB + b1);
      bf16x8 o;
      o[0] = (bf16)lo[0]; o[1] = (bf16)lo[1]; o[2] = (bf16)lo[2]; o[3] = (bf16)lo[3];
      o[4] = (bf16)hi[0]; o[5] = (bf16)hi[1]; o[6] = (bf16)hi[2]; o[7] = (bf16)hi[3];
      af[m] = o;
    }
#pragma unroll
    for (int n = 0; n < 2; ++n)
      bfr[n] = *(const bf16x8*)&Bs[cur][(wn * 32 + n * 16 + lr) * 32 + lk * 8];

    __builtin_amdgcn_s_setprio(1);
#pragma unroll
    for (int m = 0; m < 4; ++m)
#pragma unroll
      for (int n = 0; n < 2; ++n)
        acc[m][n] = __builtin_amdgcn_mfma_f32_16x16x32_bf16(af[m], bfr[n], acc[m][n], 0, 0, 0);
    __builtin_amdgcn_s_setprio(0);
    __builtin_amdgcn_sched_barrier(0);

    if (kt < 31) {
      asm volatile("s_waitcnt vmcnt(0)" ::: "memory");
      __builtin_amdgcn_s_barrier();
    }
  }

#pragma unroll
  for (int m = 0; m < 4; ++m)
#pragma unroll
    for (int n = 0; n < 2; ++n) {
      const int gc = bn * 64 + wn * 32 + n * 16 + lr;
      const float bv = bias[gc];
      if (z == 2) {
        bf16x4 pk;
#pragma unroll
        for (int r = 0; r < 4; ++r) pk[r] = (bf16)(acc[m][n][r] + bv);
        const int gr0 = bm * 128 + wm * 64 + m * 16 + lk * 4;
        const int nb = gr0 >> 10, l0 = gr0 & 1023;
        const int hh = gc >> 7, d = gc & 127;
        *(bf16x4*)(C + ((size_t)(nb * 8 + hh) * 128 + d) * 1024 + l0) = pk;
      } else {
#pragma unroll
        for (int r = 0; r < 4; ++r) {
          const int gr = bm * 128 + wm * 64 + m * 16 + lk * 4 + r;
          C[(size_t)gr * 1024 + gc] = (bf16)(acc[m][n][r] + bv);
        }
      }
    }
}

// ---------------- output projection GEMM: 128x64 tiles, 512 blocks ----------
__global__ __launch_bounds__(256) void gemm_out(
    const bf16* __restrict__ A, const bf16* __restrict__ B,
    const float* __restrict__ bias, float* __restrict__ C) {
  const int f = blockIdx.x + (blockIdx.y << 4);
  const int g = (f & 7) * 64 + (f >> 3);  // 512 % 8 == 0: bijective
  const int bn = g & 15;
  const int bm = g >> 4;

  const int t = threadIdx.x;
  const int lane = t & 63, w = t >> 6;
  const int lr = lane & 15, lk = lane >> 4;
  const int wm = w >> 1, wn = w & 1;

  __shared__ __align__(16) bf16 As[3][128 * 32];
  __shared__ __align__(16) bf16 Bs[3][64 * 32];

  auto STAGE = [&](bf16* Ad, bf16* Bd, int kt) {
#pragma unroll
    for (int p = 0; p < 2; ++p) {
      const int idx = p * 256 + t;
      const int row = idx >> 2;
      const int col = (idx & 3) * 8;
      const int ldso = (p * 256 + (t & ~63)) * 8;
      GLD_LDS(A + (size_t)(bm * 128 + row) * 1024 + kt * 32 + col, Ad + ldso);
    }
    {
      const int row = t >> 2;
      const int col = (t & 3) * 8;
      const int ldso = (t & ~63) * 8;
      GLD_LDS(B + (size_t)(bn * 64 + row) * 1024 + kt * 32 + col, Bd + ldso);
    }
  };

  f32x4 acc[4][2];
#pragma unroll
  for (int m = 0; m < 4; ++m)
#pragma unroll
    for (int n = 0; n < 2; ++n) acc[m][n] = {0.f, 0.f, 0.f, 0.f};

  bf16 *a0 = As[0], *a1 = As[1], *a2 = As[2];
  bf16 *b0 = Bs[0], *b1 = Bs[1], *b2 = Bs[2];

  STAGE(a0, b0, 0);
  STAGE(a1, b1, 1);
  asm volatile("s_waitcnt vmcnt(3)" ::: "memory");
  __builtin_amdgcn_s_barrier();

  for (int kt = 0; kt < 32; ++kt) {
    if (kt < 30) STAGE(a2, b2, kt + 2);
    __builtin_amdgcn_sched_barrier(0);

    bf16x8 af[4], bfr[2];
#pragma unroll
    for (int m = 0; m < 4; ++m)
      af[m] = *(const bf16x8*)&a0[(wm * 64 + m * 16 + lr) * 32 + lk * 8];
#pragma unroll
    for (int n = 0; n < 2; ++n)
      bfr[n] = *(const bf16x8*)&b0[(wn * 32 + n * 16 + lr) * 32 + lk * 8];
    __builtin_amdgcn_s_setprio(1);
#pragma unroll
    for (int m = 0; m < 4; ++m)
#pragma unroll
      for (int n = 0; n < 2; ++n)
        acc[m][n] = __builtin_amdgcn_mfma_f32_16x16x32_bf16(af[m], bfr[n], acc[m][n], 0, 0, 0);
    __builtin_amdgcn_s_setprio(0);

    if (kt < 30) {
      asm volatile("s_waitcnt vmcnt(3)" ::: "memory");
    } else if (kt == 30) {
      asm volatile("s_waitcnt vmcnt(0)" ::: "memory");
    }
    if (kt < 31) __builtin_amdgcn_s_barrier();

    bf16* ta = a0; a0 = a1; a1 = a2; a2 = ta;
    bf16* tb = b0; b0 = b1; b1 = b2; b2 = tb;
  }

#pragma unroll
  for (int m = 0; m < 4; ++m)
#pragma unroll
    for (int n = 0; n < 2; ++n) {
      const int gc = bn * 64 + wn * 32 + n * 16 + lr;
      const float bv = bias[gc];
#pragma unroll
      for (int r = 0; r < 4; ++r) {
        const int gr = bm * 128 + wm * 64 + m * 16 + lk * 4 + r;
        C[(size_t)(gr & 3) * 1048576 + (size_t)(gr >> 2) * 1024 + gc] =
            acc[m][n][r] + bv;
      }
    }
}

// ---------------- flash attention (round-6 version, unchanged) --------------
__global__ __launch_bounds__(256, 4) void attn_fwd(const bf16* __restrict__ Qg,
                                                   const bf16* __restrict__ Kg,
                                                   const bf16* __restrict__ Vtg,
                                                   bf16* __restrict__ X) {
  const int bh = blockIdx.x;  // n*8+h
  const int qt = blockIdx.y;
  const int n = bh >> 3, h = bh & 7;
  const int t = threadIdx.x;
  const int lane = t & 63, w = t >> 6;
  const int lr = lane & 15, lk = lane >> 4;
  const int qsub = w & 1, kvh = w >> 1;

  __shared__ __align__(16) char smem[40960];
  char* KsB = smem;
  char* VsB = smem + 16384;
  char* PbB = smem + 32768 + w * 2048;

  const float scale2 = 0.12754136351576995f;  // 1/sqrt(128) * log2(e)

  const bf16* qp = Qg + ((size_t)n * 1024 + qt * 32 + qsub * 16 + lr) * 1024 + h * 128;
  bf16x8 qf[4];
#pragma unroll
  for (int kc = 0; kc < 4; ++kc) {
    bf16x8 raw = *(const bf16x8*)(qp + kc * 32 + lk * 8);
#pragma unroll
    for (int j = 0; j < 8; ++j) qf[kc][j] = (bf16)((float)raw[j] * scale2);
  }

  float mrow[4], srow[4];
  f32x4 oacc[8];
#pragma unroll
  for (int r = 0; r < 4; ++r) { mrow[r] = -1e30f; srow[r] = 0.f; }
#pragma unroll
  for (int nd = 0; nd < 8; ++nd) oacc[nd] = {0.f, 0.f, 0.f, 0.f};

  for (int i = 0; i < 16; ++i) {
    __syncthreads();

#pragma unroll
    for (int g = 0; g < 4; ++g) {
      const int r = w * 16 + g * 4 + lk;
      const int c = (lane & 15) ^ (r & 7);
      GLD_LDS(Kg + ((size_t)n * 1024 + i * 64 + r) * 1024 + h * 128 + c * 8,
              KsB + (w * 16 + g * 4) * 256);
    }
#pragma unroll
    for (int g = 0; g < 4; ++g) {
      const int d = w * 32 + g * 8 + (lane >> 3);
      const int c = (lane & 7) ^ (d & 7);
      GLD_LDS(Vtg + ((size_t)bh * 128 + d) * 1024 + i * 64 + c * 8,
              VsB + (w * 32 + g * 8) * 128);
    }
    asm volatile("s_waitcnt vmcnt(0)" ::: "memory");
    __syncthreads();

    f32x4 s4[2];
    s4[0] = {0.f, 0.f, 0.f, 0.f};
    s4[1] = {0.f, 0.f, 0.f, 0.f};
    __builtin_amdgcn_s_setprio(1);
#pragma unroll
    for (int kc = 0; kc < 4; ++kc)
#pragma unroll
      for (int nf = 0; nf < 2; ++nf) {
        const int s = kvh * 32 + nf * 16 + lr;
        const int byte = (s * 256 + kc * 64 + lk * 16) ^ ((s & 7) << 4);
        bf16x8 kf = *(const bf16x8*)(KsB + byte);
        s4[nf] = __builtin_amdgcn_mfma_f32_16x16x32_bf16(qf[kc], kf, s4[nf], 0, 0, 0);
      }
    __builtin_amdgcn_s_setprio(0);

    float pv[2][4];
    int okf = 1;
#pragma unroll
    for (int r = 0; r < 4; ++r) {
      pv[0][r] = s4[0][r];
      pv[1][r] = s4[1][r];
      okf &= (fmaxf(pv[0][r], pv[1][r]) <= mrow[r] + 8.0f) ? 1 : 0;
    }
    if (!__all(okf)) {
#pragma unroll
      for (int r = 0; r < 4; ++r) {
        float mx = fmaxf(pv[0][r], pv[1][r]);
        mx = fmaxf(mx, __shfl_xor(mx, 1, 16));
        mx = fmaxf(mx, __shfl_xor(mx, 2, 16));
        mx = fmaxf(mx, __shfl_xor(mx, 4, 16));
        mx = fmaxf(mx, __shfl_xor(mx, 8, 16));
        const float mnew = fmaxf(mrow[r], mx);
        const float fold = __builtin_amdgcn_exp2f(mrow[r] - mnew);
        mrow[r] = mnew;
        srow[r] *= fold;
#pragma unroll
        for (int nd = 0; nd < 8; ++nd) oacc[nd][r] *= fold;
      }
    }
#pragma unroll
    for (int r = 0; r < 4; ++r) {
      const float e0 = __builtin_amdgcn_exp2f(pv[0][r] - mrow[r]);
      const float e1 = __builtin_amdgcn_exp2f(pv[1][r] - mrow[r]);
      pv[0][r] = e0; pv[1][r] = e1;
      srow[r] += e0 + e1;
    }

#pragma unroll
    for (int nf = 0; nf < 2; ++nf)
#pragma unroll
      for (int r = 0; r < 4; ++r) {
        const int q = lk * 4 + r, s = nf * 16 + lr;
        const int byte = (q * 128 + s * 2) ^ ((q & 7) << 4);
        *(bf16*)(PbB + byte) = (bf16)pv[nf][r];
      }
    asm volatile("s_waitcnt lgkmcnt(0)" ::: "memory");
    __builtin_amdgcn_sched_barrier(0);

    const int pbyte = (lr * 128 + lk * 16) ^ ((lr & 7) << 4);
    bf16x8 pf = *(const bf16x8*)(PbB + pbyte);
    __builtin_amdgcn_s_setprio(1);
#pragma unroll
    for (int nd = 0; nd < 8; ++nd) {
      const int d = nd * 16 + lr;
      const int vbyte = (d * 128 + kvh * 64 + lk * 16) ^ ((d & 7) << 4);
      bf16x8 vf = *(const bf16x8*)(VsB + vbyte);
      oacc[nd] = __builtin_amdgcn_mfma_f32_16x16x32_bf16(pf, vf, oacc[nd], 0, 0, 0);
    }
    __builtin_amdgcn_s_setprio(0);
  }

#pragma unroll
  for (int r = 0; r < 4; ++r) {
    float s = srow[r];
    s += __shfl_xor(s, 1, 16);
    s += __shfl_xor(s, 2, 16);
    s += __shfl_xor(s, 4, 16);
    s += __shfl_xor(s, 8, 16);
    srow[r] = s;
  }

  __syncthreads();
  float* Ol = (float*)smem + qsub * (16 * 128);
  float* Ms = (float*)(smem + 16384) + qsub * 32;
  if (kvh == 1) {
#pragma unroll
    for (int nd = 0; nd < 8; ++nd)
#pragma unroll
      for (int r = 0; r < 4; ++r)
        Ol[(lk * 4 + r) * 128 + nd * 16 + lr] = oacc[nd][r];
    if (lr == 0) {
#pragma unroll
      for (int r = 0; r < 4; ++r) {
        Ms[(lk * 4 + r) * 2 + 0] = mrow[r];
        Ms[(lk * 4 + r) * 2 + 1] = srow[r];
      }
    }
  }
  __syncthreads();
  if (kvh == 0) {
    float rs1[4], rs2[4];
#pragma unroll
    for (int r = 0; r < 4; ++r) {
      const float m2 = Ms[(lk * 4 + r) * 2 + 0];
      const float s2 = Ms[(lk * 4 + r) * 2 + 1];
      const float mN = fmaxf(mrow[r], m2);
      const float w1 = __builtin_amdgcn_exp2f(mrow[r] - mN);
      const float w2 = __builtin_amdgcn_exp2f(m2 - mN);
      const float rd = 1.f / (srow[r] * w1 + s2 * w2);
      rs1[r] = w1 * rd; rs2[r] = w2 * rd;
    }
#pragma unroll
    for (int nd = 0; nd < 8; ++nd)
#pragma unroll
      for (int r = 0; r < 4; ++r) {
        const float o = oacc[nd][r] * rs1[r] +
                        Ol[(lk * 4 + r) * 128 + nd * 16 + lr] * rs2[r];
        const int l = qt * 32 + qsub * 16 + lk * 4 + r;
        const int d = nd * 16 + lr;
        X[((size_t)l * 32 + bh) * 128 + d] = (bf16)o;
      }
  }
}

// ---------------- launch ----------------------------------------------------
extern "C" void kernel_launch(void* const* d_in, const int* in_sizes, int n_in,
                              void* d_out, int out_size, void* d_ws, size_t ws_size,
                              hipStream_t stream) {
  const float* query = (const float*)d_in[0];
  const float* key_i = (const float*)d_in[1];
  const float* value = (const float*)d_in[2];
  const float* q_w = (const float*)d_in[5];
  const float* q_b = (const float*)d_in[6];
  const float* k_w = (const float*)d_in[7];
  const float* k_b = (const float*)d_in[8];
  const float* v_w = (const float*)d_in[9];
  const float* v_b = (const float*)d_in[10];
  const float* o_w = (const float*)d_in[11];
  const float* o_b = (const float*)d_in[12];

  char* p = (char*)d_ws;
  bf16* wq  = (bf16*)p; p += (size_t)1024 * 1024 * 2;
  bf16* wk  = (bf16*)p; p += (size_t)1024 * 1024 * 2;
  bf16* wv  = (bf16*)p; p += (size_t)1024 * 1024 * 2;
  bf16* wo  = (bf16*)p; p += (size_t)1024 * 1024 * 2;
  bf16* Qb  = (bf16*)p; p += (size_t)4096 * 1024 * 2;
  bf16* Kb  = (bf16*)p; p += (size_t)4096 * 1024 * 2;
  bf16* Vtg = (bf16*)p; p += (size_t)4096 * 1024 * 2;  // [bh][d][s]
  bf16* Xb  = (bf16*)p; p += (size_t)4096 * 1024 * 2;

  CvtSegs cs;
  cs.src[0] = q_w; cs.dst[0] = wq; cs.n8[0] = 131072;
  cs.src[1] = k_w; cs.dst[1] = wk; cs.n8[1] = 131072;
  cs.src[2] = v_w; cs.dst[2] = wv; cs.n8[2] = 131072;
  cs.src[3] = o_w; cs.dst[3] = wo; cs.n8[3] = 131072;
  cs.total8 = 4 * 131072;
  cvt_all<<<(cs.total8 + 255) / 256, 256, 0, stream>>>(cs);

  gemm_qkv<<<dim3(16, 32, 3), 256, 0, stream>>>(query, key_i, value,
                                                wq, wk, wv,
                                                q_b, k_b, v_b, Qb, Kb, Vtg);
  attn_fwd<<<dim3(32, 32), 256, 0, stream>>>(Qb, Kb, Vtg, Xb);
  gemm_out<<<dim3(16, 32), 256, 0, stream>>>(Xb, wo, o_b, (float*)d_out);
}

// Round 16
// 107.062 us; speedup vs baseline: 1.1579x; 1.1579x over previous
//
#include <hip/hip_runtime.h>
#include <hip/hip_bf16.h>

typedef __bf16 bf16;
typedef __bf16 bf16x4 __attribute__((ext_vector_type(4)));
typedef __bf16 bf16x8 __attribute__((ext_vector_type(8)));
typedef float  f32x4  __attribute__((ext_vector_type(4)));

#define GLD_LDS(g, l) __builtin_amdgcn_global_load_lds(                        \
    (const __attribute__((address_space(1))) unsigned int*)(g),                \
    (__attribute__((address_space(3))) unsigned int*)(l), 16, 0, 0)

// ---------------- f32 -> bf16 conversion (weights only) ---------------------
struct CvtSegs {
  const float* src[4];
  bf16* dst[4];
  int n8[4];
  int total8;
};

__global__ __launch_bounds__(256) void cvt_all(CvtSegs s) {
  int i = blockIdx.x * 256 + threadIdx.x;
  if (i >= s.total8) return;
  int seg = 0, off = i;
  while (off >= s.n8[seg]) { off -= s.n8[seg]; ++seg; }
  const float4* sp = reinterpret_cast<const float4*>(s.src[seg]);
  float4 a = sp[2 * off], b = sp[2 * off + 1];
  bf16x8 o;
  o[0] = (bf16)a.x; o[1] = (bf16)a.y; o[2] = (bf16)a.z; o[3] = (bf16)a.w;
  o[4] = (bf16)b.x; o[5] = (bf16)b.y; o[6] = (bf16)b.z; o[7] = (bf16)b.w;
  reinterpret_cast<bf16x8*>(s.dst[seg])[off] = o;
}

// ---------------- QKV GEMM, A read directly as f32, 2-phase pipelined -------
// r14 structure (best measured, 107.9 total) + B source-chunk XOR swizzle:
// the [128][32]bf16 B tile read at row*64B was an 8-way bank conflict
// (start banks only 0/16); staging global chunk (idx&3)^(row&3) and reading
// chunk lk^(row&3) spreads start banks 4-ways -> ~half the conflict cycles.
// A staged RAW f32 (source-chunk swizzle, 2-way free); fragments cvt'd on
// ds_read.  STAGE(t+1) before compute(t); one vmcnt(0)+s_barrier per iter.
// z==2 writes V^T [bh][d][s].
__global__ __launch_bounds__(256) void gemm_qkv(
    const float* __restrict__ A0, const float* __restrict__ A1, const float* __restrict__ A2,
    const bf16* __restrict__ B0, const bf16* __restrict__ B1, const bf16* __restrict__ B2,
    const float* __restrict__ bias0, const float* __restrict__ bias1, const float* __restrict__ bias2,
    bf16* __restrict__ C0, bf16* __restrict__ C1, bf16* __restrict__ C2) {
  const int f = blockIdx.x + (blockIdx.y << 3) + (blockIdx.z << 8);
  const int g = (f & 7) * 96 + (f >> 3);  // 768 % 8 == 0: bijective
  const int bn = g & 7;
  const int bm = (g >> 3) & 31;
  const int z = g >> 8;

  const float* A = (z == 0) ? A0 : (z == 1) ? A1 : A2;
  const bf16* B = (z == 0) ? B0 : (z == 1) ? B1 : B2;
  const float* bias = (z == 0) ? bias0 : (z == 1) ? bias1 : bias2;
  bf16* C = (z == 0) ? C0 : (z == 1) ? C1 : C2;

  const int t = threadIdx.x;
  const int lane = t & 63, w = t >> 6;
  const int lr = lane & 15, lk = lane >> 4;
  const int wm = w >> 1, wn = w & 1;

  __shared__ __align__(16) float Afs[2][128 * 32];   // 2 x 16KB
  __shared__ __align__(16) bf16  Bs[2][128 * 32];    // 2 x 8KB

  auto STAGE = [&](int buf, int kt) {
#pragma unroll
    for (int gg = 0; gg < 4; ++gg) {
      const int row = w * 32 + gg * 8 + (lane >> 3);
      const int cg = (lane & 7) ^ (row & 7);  // pre-swizzled source chunk
      GLD_LDS(A + (size_t)(bm * 128 + row) * 1024 + kt * 32 + cg * 4,
              &Afs[buf][(w * 32 + gg * 8) * 32]);
    }
#pragma unroll
    for (int p = 0; p < 2; ++p) {
      const int idx = p * 256 + t;
      const int row = idx >> 2;
      const int ck = (idx & 3) ^ (row & 3);   // B source-chunk swizzle
      const int ldso = (p * 256 + (t & ~63)) * 8;
      GLD_LDS(B + (size_t)(bn * 128 + row) * 1024 + kt * 32 + ck * 8, &Bs[buf][ldso]);
    }
  };

  f32x4 acc[4][4];
#pragma unroll
  for (int m = 0; m < 4; ++m)
#pragma unroll
    for (int n = 0; n < 4; ++n) acc[m][n] = {0.f, 0.f, 0.f, 0.f};

  // prologue: tile 0 staged and drained
  STAGE(0, 0);
  asm volatile("s_waitcnt vmcnt(0)" ::: "memory");
  __builtin_amdgcn_s_barrier();

  for (int kt = 0; kt < 32; ++kt) {
    const int cur = kt & 1;
    if (kt < 31) STAGE(cur ^ 1, kt + 1);  // in flight across compute phase
    __builtin_amdgcn_sched_barrier(0);

    // --- fragments: A f32 -> cvt bf16; B swizzled read ----------------------
    char* AfB = (char*)&Afs[cur][0];
    bf16x8 af[4], bfr[4];
#pragma unroll
    for (int m = 0; m < 4; ++m) {
      const int row = wm * 64 + m * 16 + lr;
      const int sw = row & 7;
      const int b0 = row * 128 + ((2 * lk) ^ sw) * 16;
      const int b1 = row * 128 + ((2 * lk + 1) ^ sw) * 16;
      f32x4 lo = *(const f32x4*)(AfB + b0);
      f32x4 hi = *(const f32x4*)(AfB + b1);
      bf16x8 o;
      o[0] = (bf16)lo[0]; o[1] = (bf16)lo[1]; o[2] = (bf16)lo[2]; o[3] = (bf16)lo[3];
      o[4] = (bf16)hi[0]; o[5] = (bf16)hi[1]; o[6] = (bf16)hi[2]; o[7] = (bf16)hi[3];
      af[m] = o;
    }
#pragma unroll
    for (int n = 0; n < 4; ++n) {
      const int row = wn * 64 + n * 16 + lr;
      bfr[n] = *(const bf16x8*)&Bs[cur][row * 32 + (lk ^ (row & 3)) * 8];
    }

    __builtin_amdgcn_s_setprio(1);
#pragma unroll
    for (int m = 0; m < 4; ++m)
#pragma unroll
      for (int n = 0; n < 4; ++n)
        acc[m][n] = __builtin_amdgcn_mfma_f32_16x16x32_bf16(af[m], bfr[n], acc[m][n], 0, 0, 0);
    __builtin_amdgcn_s_setprio(0);
    __builtin_amdgcn_sched_barrier(0);

    if (kt < 31) {
      asm volatile("s_waitcnt vmcnt(0)" ::: "memory");
      __builtin_amdgcn_s_barrier();
    }
  }

#pragma unroll
  for (int m = 0; m < 4; ++m)
#pragma unroll
    for (int n = 0; n < 4; ++n) {
      const int gc = bn * 128 + wn * 64 + n * 16 + lr;
      const float bv = bias[gc];
      if (z == 2) {
        bf16x4 pk;
#pragma unroll
        for (int r = 0; r < 4; ++r) pk[r] = (bf16)(acc[m][n][r] + bv);
        const int gr0 = bm * 128 + wm * 64 + m * 16 + lk * 4;
        const int nb = gr0 >> 10, l0 = gr0 & 1023;
        const int hh = gc >> 7, d = gc & 127;
        *(bf16x4*)(C + ((size_t)(nb * 8 + hh) * 128 + d) * 1024 + l0) = pk;
      } else {
#pragma unroll
        for (int r = 0; r < 4; ++r) {
          const int gr = bm * 128 + wm * 64 + m * 16 + lk * 4 + r;
          C[(size_t)gr * 1024 + gc] = (bf16)(acc[m][n][r] + bv);
        }
      }
    }
}

// ---------------- output projection GEMM: 128x64 tiles, 512 blocks ----------
// r14 structure + A/B source-chunk XOR swizzle (same 8-way -> 4-way fix).
__global__ __launch_bounds__(256) void gemm_out(
    const bf16* __restrict__ A, const bf16* __restrict__ B,
    const float* __restrict__ bias, float* __restrict__ C) {
  const int f = blockIdx.x + (blockIdx.y << 4);
  const int g = (f & 7) * 64 + (f >> 3);  // 512 % 8 == 0: bijective
  const int bn = g & 15;
  const int bm = g >> 4;

  const int t = threadIdx.x;
  const int lane = t & 63, w = t >> 6;
  const int lr = lane & 15, lk = lane >> 4;
  const int wm = w >> 1, wn = w & 1;

  __shared__ __align__(16) bf16 As[3][128 * 32];
  __shared__ __align__(16) bf16 Bs[3][64 * 32];

  auto STAGE = [&](bf16* Ad, bf16* Bd, int kt) {
#pragma unroll
    for (int p = 0; p < 2; ++p) {
      const int idx = p * 256 + t;
      const int row = idx >> 2;
      const int ck = (idx & 3) ^ (row & 3);
      const int ldso = (p * 256 + (t & ~63)) * 8;
      GLD_LDS(A + (size_t)(bm * 128 + row) * 1024 + kt * 32 + ck * 8, Ad + ldso);
    }
    {
      const int row = t >> 2;
      const int ck = (t & 3) ^ (row & 3);
      const int ldso = (t & ~63) * 8;
      GLD_LDS(B + (size_t)(bn * 64 + row) * 1024 + kt * 32 + ck * 8, Bd + ldso);
    }
  };

  f32x4 acc[4][2];
#pragma unroll
  for (int m = 0; m < 4; ++m)
#pragma unroll
    for (int n = 0; n < 2; ++n) acc[m][n] = {0.f, 0.f, 0.f, 0.f};

  bf16 *a0 = As[0], *a1 = As[1], *a2 = As[2];
  bf16 *b0 = Bs[0], *b1 = Bs[1], *b2 = Bs[2];

  STAGE(a0, b0, 0);
  STAGE(a1, b1, 1);
  asm volatile("s_waitcnt vmcnt(3)" ::: "memory");
  __builtin_amdgcn_s_barrier();

  for (int kt = 0; kt < 32; ++kt) {
    if (kt < 30) STAGE(a2, b2, kt + 2);
    __builtin_amdgcn_sched_barrier(0);

    bf16x8 af[4], bfr[2];
#pragma unroll
    for (int m = 0; m < 4; ++m) {
      const int row = wm * 64 + m * 16 + lr;
      af[m] = *(const bf16x8*)&a0[row * 32 + (lk ^ (row & 3)) * 8];
    }
#pragma unroll
    for (int n = 0; n < 2; ++n) {
      const int row = wn * 32 + n * 16 + lr;
      bfr[n] = *(const bf16x8*)&b0[row * 32 + (lk ^ (row & 3)) * 8];
    }
    __builtin_amdgcn_s_setprio(1);
#pragma unroll
    for (int m = 0; m < 4; ++m)
#pragma unroll
      for (int n = 0; n < 2; ++n)
        acc[m][n] = __builtin_amdgcn_mfma_f32_16x16x32_bf16(af[m], bfr[n], acc[m][n], 0, 0, 0);
    __builtin_amdgcn_s_setprio(0);

    if (kt < 30) {
      asm volatile("s_waitcnt vmcnt(3)" ::: "memory");
    } else if (kt == 30) {
      asm volatile("s_waitcnt vmcnt(0)" ::: "memory");
    }
    if (kt < 31) __builtin_amdgcn_s_barrier();

    bf16* ta = a0; a0 = a1; a1 = a2; a2 = ta;
    bf16* tb = b0; b0 = b1; b1 = b2; b2 = tb;
  }

#pragma unroll
  for (int m = 0; m < 4; ++m)
#pragma unroll
    for (int n = 0; n < 2; ++n) {
      const int gc = bn * 64 + wn * 32 + n * 16 + lr;
      const float bv = bias[gc];
#pragma unroll
      for (int r = 0; r < 4; ++r) {
        const int gr = bm * 128 + wm * 64 + m * 16 + lk * 4 + r;
        C[(size_t)(gr & 3) * 1048576 + (size_t)(gr >> 2) * 1024 + gc] =
            acc[m][n][r] + bv;
      }
    }
}

// ---------------- flash attention (round-6 version, unchanged) --------------
__global__ __launch_bounds__(256, 4) void attn_fwd(const bf16* __restrict__ Qg,
                                                   const bf16* __restrict__ Kg,
                                                   const bf16* __restrict__ Vtg,
                                                   bf16* __restrict__ X) {
  const int bh = blockIdx.x;  // n*8+h
  const int qt = blockIdx.y;
  const int n = bh >> 3, h = bh & 7;
  const int t = threadIdx.x;
  const int lane = t & 63, w = t >> 6;
  const int lr = lane & 15, lk = lane >> 4;
  const int qsub = w & 1, kvh = w >> 1;

  __shared__ __align__(16) char smem[40960];
  char* KsB = smem;
  char* VsB = smem + 16384;
  char* PbB = smem + 32768 + w * 2048;

  const float scale2 = 0.12754136351576995f;  // 1/sqrt(128) * log2(e)

  const bf16* qp = Qg + ((size_t)n * 1024 + qt * 32 + qsub * 16 + lr) * 1024 + h * 128;
  bf16x8 qf[4];
#pragma unroll
  for (int kc = 0; kc < 4; ++kc) {
    bf16x8 raw = *(const bf16x8*)(qp + kc * 32 + lk * 8);
#pragma unroll
    for (int j = 0; j < 8; ++j) qf[kc][j] = (bf16)((float)raw[j] * scale2);
  }

  float mrow[4], srow[4];
  f32x4 oacc[8];
#pragma unroll
  for (int r = 0; r < 4; ++r) { mrow[r] = -1e30f; srow[r] = 0.f; }
#pragma unroll
  for (int nd = 0; nd < 8; ++nd) oacc[nd] = {0.f, 0.f, 0.f, 0.f};

  for (int i = 0; i < 16; ++i) {
    __syncthreads();

#pragma unroll
    for (int g = 0; g < 4; ++g) {
      const int r = w * 16 + g * 4 + lk;
      const int c = (lane & 15) ^ (r & 7);
      GLD_LDS(Kg + ((size_t)n * 1024 + i * 64 + r) * 1024 + h * 128 + c * 8,
              KsB + (w * 16 + g * 4) * 256);
    }
#pragma unroll
    for (int g = 0; g < 4; ++g) {
      const int d = w * 32 + g * 8 + (lane >> 3);
      const int c = (lane & 7) ^ (d & 7);
      GLD_LDS(Vtg + ((size_t)bh * 128 + d) * 1024 + i * 64 + c * 8,
              VsB + (w * 32 + g * 8) * 128);
    }
    asm volatile("s_waitcnt vmcnt(0)" ::: "memory");
    __syncthreads();

    f32x4 s4[2];
    s4[0] = {0.f, 0.f, 0.f, 0.f};
    s4[1] = {0.f, 0.f, 0.f, 0.f};
    __builtin_amdgcn_s_setprio(1);
#pragma unroll
    for (int kc = 0; kc < 4; ++kc)
#pragma unroll
      for (int nf = 0; nf < 2; ++nf) {
        const int s = kvh * 32 + nf * 16 + lr;
        const int byte = (s * 256 + kc * 64 + lk * 16) ^ ((s & 7) << 4);
        bf16x8 kf = *(const bf16x8*)(KsB + byte);
        s4[nf] = __builtin_amdgcn_mfma_f32_16x16x32_bf16(qf[kc], kf, s4[nf], 0, 0, 0);
      }
    __builtin_amdgcn_s_setprio(0);

    float pv[2][4];
    int okf = 1;
#pragma unroll
    for (int r = 0; r < 4; ++r) {
      pv[0][r] = s4[0][r];
      pv[1][r] = s4[1][r];
      okf &= (fmaxf(pv[0][r], pv[1][r]) <= mrow[r] + 8.0f) ? 1 : 0;
    }
    if (!__all(okf)) {
#pragma unroll
      for (int r = 0; r < 4; ++r) {
        float mx = fmaxf(pv[0][r], pv[1][r]);
        mx = fmaxf(mx, __shfl_xor(mx, 1, 16));
        mx = fmaxf(mx, __shfl_xor(mx, 2, 16));
        mx = fmaxf(mx, __shfl_xor(mx, 4, 16));
        mx = fmaxf(mx, __shfl_xor(mx, 8, 16));
        const float mnew = fmaxf(mrow[r], mx);
        const float fold = __builtin_amdgcn_exp2f(mrow[r] - mnew);
        mrow[r] = mnew;
        srow[r] *= fold;
#pragma unroll
        for (int nd = 0; nd < 8; ++nd) oacc[nd][r] *= fold;
      }
    }
#pragma unroll
    for (int r = 0; r < 4; ++r) {
      const float e0 = __builtin_amdgcn_exp2f(pv[0][r] - mrow[r]);
      const float e1 = __builtin_amdgcn_exp2f(pv[1][r] - mrow[r]);
      pv[0][r] = e0; pv[1][r] = e1;
      srow[r] += e0 + e1;
    }

#pragma unroll
    for (int nf = 0; nf < 2; ++nf)
#pragma unroll
      for (int r = 0; r < 4; ++r) {
        const int q = lk * 4 + r, s = nf * 16 + lr;
        const int byte = (q * 128 + s * 2) ^ ((q & 7) << 4);
        *(bf16*)(PbB + byte) = (bf16)pv[nf][r];
      }
    asm volatile("s_waitcnt lgkmcnt(0)" ::: "memory");
    __builtin_amdgcn_sched_barrier(0);

    const int pbyte = (lr * 128 + lk * 16) ^ ((lr & 7) << 4);
    bf16x8 pf = *(const bf16x8*)(PbB + pbyte);
    __builtin_amdgcn_s_setprio(1);
#pragma unroll
    for (int nd = 0; nd < 8; ++nd) {
      const int d = nd * 16 + lr;
      const int vbyte = (d * 128 + kvh * 64 + lk * 16) ^ ((d & 7) << 4);
      bf16x8 vf = *(const bf16x8*)(VsB + vbyte);
      oacc[nd] = __builtin_amdgcn_mfma_f32_16x16x32_bf16(pf, vf, oacc[nd], 0, 0, 0);
    }
    __builtin_amdgcn_s_setprio(0);
  }

#pragma unroll
  for (int r = 0; r < 4; ++r) {
    float s = srow[r];
    s += __shfl_xor(s, 1, 16);
    s += __shfl_xor(s, 2, 16);
    s += __shfl_xor(s, 4, 16);
    s += __shfl_xor(s, 8, 16);
    srow[r] = s;
  }

  __syncthreads();
  float* Ol = (float*)smem + qsub * (16 * 128);
  float* Ms = (float*)(smem + 16384) + qsub * 32;
  if (kvh == 1) {
#pragma unroll
    for (int nd = 0; nd < 8; ++nd)
#pragma unroll
      for (int r = 0; r < 4; ++r)
        Ol[(lk * 4 + r) * 128 + nd * 16 + lr] = oacc[nd][r];
    if (lr == 0) {
#pragma unroll
      for (int r = 0; r < 4; ++r) {
        Ms[(lk * 4 + r) * 2 + 0] = mrow[r];
        Ms[(lk * 4 + r) * 2 + 1] = srow[r];
      }
    }
  }
  __syncthreads();
  if (kvh == 0) {
    float rs1[4], rs2[4];
#pragma unroll
    for (int r = 0; r < 4; ++r) {
      const float m2 = Ms[(lk * 4 + r) * 2 + 0];
      const float s2 = Ms[(lk * 4 + r) * 2 + 1];
      const float mN = fmaxf(mrow[r], m2);
      const float w1 = __builtin_amdgcn_exp2f(mrow[r] - mN);
      const float w2 = __builtin_amdgcn_exp2f(m2 - mN);
      const float rd = 1.f / (srow[r] * w1 + s2 * w2);
      rs1[r] = w1 * rd; rs2[r] = w2 * rd;
    }
#pragma unroll
    for (int nd = 0; nd < 8; ++nd)
#pragma unroll
      for (int r = 0; r < 4; ++r) {
        const float o = oacc[nd][r] * rs1[r] +
                        Ol[(lk * 4 + r) * 128 + nd * 16 + lr] * rs2[r];
        const int l = qt * 32 + qsub * 16 + lk * 4 + r;
        const int d = nd * 16 + lr;
        X[((size_t)l * 32 + bh) * 128 + d] = (bf16)o;
      }
  }
}

// ---------------- launch ----------------------------------------------------
extern "C" void kernel_launch(void* const* d_in, const int* in_sizes, int n_in,
                              void* d_out, int out_size, void* d_ws, size_t ws_size,
                              hipStream_t stream) {
  const float* query = (const float*)d_in[0];
  const float* key_i = (const float*)d_in[1];
  const float* value = (const float*)d_in[2];
  const float* q_w = (const float*)d_in[5];
  const float* q_b = (const float*)d_in[6];
  const float* k_w = (const float*)d_in[7];
  const float* k_b = (const float*)d_in[8];
  const float* v_w = (const float*)d_in[9];
  const float* v_b = (const float*)d_in[10];
  const float* o_w = (const float*)d_in[11];
  const float* o_b = (const float*)d_in[12];

  char* p = (char*)d_ws;
  bf16* wq  = (bf16*)p; p += (size_t)1024 * 1024 * 2;
  bf16* wk  = (bf16*)p; p += (size_t)1024 * 1024 * 2;
  bf16* wv  = (bf16*)p; p += (size_t)1024 * 1024 * 2;
  bf16* wo  = (bf16*)p; p += (size_t)1024 * 1024 * 2;
  bf16* Qb  = (bf16*)p; p += (size_t)4096 * 1024 * 2;
  bf16* Kb  = (bf16*)p; p += (size_t)4096 * 1024 * 2;
  bf16* Vtg = (bf16*)p; p += (size_t)4096 * 1024 * 2;  // [bh][d][s]
  bf16* Xb  = (bf16*)p; p += (size_t)4096 * 1024 * 2;

  CvtSegs cs;
  cs.src[0] = q_w; cs.dst[0] = wq; cs.n8[0] = 131072;
  cs.src[1] = k_w; cs.dst[1] = wk; cs.n8[1] = 131072;
  cs.src[2] = v_w; cs.dst[2] = wv; cs.n8[2] = 131072;
  cs.src[3] = o_w; cs.dst[3] = wo; cs.n8[3] = 131072;
  cs.total8 = 4 * 131072;
  cvt_all<<<(cs.total8 + 255) / 256, 256, 0, stream>>>(cs);

  gemm_qkv<<<dim3(8, 32, 3), 256, 0, stream>>>(query, key_i, value,
                                               wq, wk, wv,
                                               q_b, k_b, v_b, Qb, Kb, Vtg);
  attn_fwd<<<dim3(32, 32), 256, 0, stream>>>(Qb, Kb, Vtg, Xb);
  gemm_out<<<dim3(16, 32), 256, 0, stream>>>(Xb, wo, o_b, (float*)d_out);
}